// Round 4
// baseline (99.889 us; speedup 1.0000x reference)
//
#include <hip/hip_runtime.h>
#include <math.h>

#define DMODEL 1024   // 16 heads x 64 dim
#define TOKW 4        // waves per block (1 token per wave per iteration)
#define NBLK 1024     // persistent-ish grid: 4096 waves, 8 tokens each

typedef _Float16 f16x4 __attribute__((ext_vector_type(4)));
typedef _Float16 f16x8 __attribute__((ext_vector_type(8)));
typedef float    f32x4 __attribute__((ext_vector_type(4)));

// ---- load one token's q/k/v into registers (pure loads, no math) ----
__device__ __forceinline__ void load_tok(const float* __restrict__ q,
                                         const float* __restrict__ k,
                                         const float* __restrict__ v,
                                         size_t base, int r, int G,
                                         f32x4 ql[4], f32x4 kl[4], float vl[4][4])
{
    const float* qrow = q + base + r * 64;
    const float* krow = k + base + r * 64;
#pragma unroll
    for (int c = 0; c < 2; ++c)
#pragma unroll
        for (int h = 0; h < 2; ++h) {
            ql[2 * c + h] = *(const f32x4*)(qrow + 32 * c + 8 * G + 4 * h);
            kl[2 * c + h] = *(const f32x4*)(krow + 32 * c + 8 * G + 4 * h);
        }
#pragma unroll
    for (int t = 0; t < 4; ++t)
#pragma unroll
        for (int cg = 0; cg < 4; ++cg)
            vl[t][cg] = v[base + (size_t)(4 * G + t) * 64 + 16 * cg + r];
}

// ---- per-token compute: QK^T (mfma) -> causal softmax (regs) -> PV (mfma) ----
__device__ __forceinline__ void compute_store(float* __restrict__ out,
                                              size_t base, int r, int G,
                                              const f32x4 ql[4], const f32x4 kl[4],
                                              const float vl[4][4])
{
    f16x8 ka[2], qb[2];
#pragma unroll
    for (int c = 0; c < 2; ++c)
#pragma unroll
        for (int h = 0; h < 2; ++h)
#pragma unroll
            for (int e = 0; e < 4; ++e) {
                ka[c][4 * h + e] = (_Float16)kl[2 * c + h][e];
                qb[c][4 * h + e] = (_Float16)ql[2 * c + h][e];
            }

    f32x4 acc = {0.f, 0.f, 0.f, 0.f};
    acc = __builtin_amdgcn_mfma_f32_16x16x32_f16(ka[0], qb[0], acc, 0, 0, 0);
    acc = __builtin_amdgcn_mfma_f32_16x16x32_f16(ka[1], qb[1], acc, 0, 0, 0);
    // lane holds S[i = r][j = 4G + e]

    float s[4];
#pragma unroll
    for (int e = 0; e < 4; ++e) {
        const int j = 4 * G + e;
        s[e] = (j > r) ? -1e30f : acc[e] * 0.125f;   // 1/sqrt(64)
    }
    float m = fmaxf(fmaxf(s[0], s[1]), fmaxf(s[2], s[3]));
    m = fmaxf(m, __shfl_xor(m, 16));
    m = fmaxf(m, __shfl_xor(m, 32));
    const float e0 = __expf(s[0] - m);
    const float e1 = __expf(s[1] - m);
    const float e2 = __expf(s[2] - m);
    const float e3 = __expf(s[3] - m);
    float sum = e0 + e1 + e2 + e3;
    sum += __shfl_xor(sum, 16);
    sum += __shfl_xor(sum, 32);
    const float inv = 1.0f / sum;
    f16x4 pa;
    pa[0] = (_Float16)(e0 * inv);
    pa[1] = (_Float16)(e1 * inv);
    pa[2] = (_Float16)(e2 * inv);
    pa[3] = (_Float16)(e3 * inv);

#pragma unroll
    for (int cg = 0; cg < 4; ++cg) {
        f16x4 vb;
#pragma unroll
        for (int t = 0; t < 4; ++t) vb[t] = (_Float16)vl[t][cg];
        f32x4 o = {0.f, 0.f, 0.f, 0.f};
        o = __builtin_amdgcn_mfma_f32_16x16x16f16(pa, vb, o, 0, 0, 0);
        float* obase = out + base + (size_t)(4 * G) * 64 + 16 * cg + r;
#pragma unroll
        for (int e = 0; e < 4; ++e)
            __builtin_nontemporal_store(o[e], obase + e * 64);  // keep L3 for inputs
    }
}

__global__ __launch_bounds__(256, 3) void temporal_attn_kernel(
    const float* __restrict__ q,
    const float* __restrict__ k,
    const float* __restrict__ v,
    float* __restrict__ out,
    int ntok)
{
    const int lane = threadIdx.x & 63;
    const int wave = threadIdx.x >> 6;
    const int r = lane & 15;
    const int G = lane >> 4;
    const int W = gridDim.x * TOKW;                 // total waves
    int t0 = blockIdx.x * TOKW + wave;              // this wave's first token
    if (t0 >= ntok) return;

    // 2-deep software pipeline: token t's loads fly while token t-1 computes.
    f32x4 qA[4], kA[4], qB[4], kB[4];
    float vA[4][4], vB[4][4];

    load_tok(q, k, v, (size_t)t0 * DMODEL, r, G, qA, kA, vA);
    for (;;) {
        const int t1 = t0 + W;
        if (t1 < ntok) {
            load_tok(q, k, v, (size_t)t1 * DMODEL, r, G, qB, kB, vB);
            compute_store(out, (size_t)t0 * DMODEL, r, G, qA, kA, vA);
            const int t2 = t1 + W;
            if (t2 < ntok) {
                load_tok(q, k, v, (size_t)t2 * DMODEL, r, G, qA, kA, vA);
                compute_store(out, (size_t)t1 * DMODEL, r, G, qB, kB, vB);
                t0 = t2;
            } else {
                compute_store(out, (size_t)t1 * DMODEL, r, G, qB, kB, vB);
                break;
            }
        } else {
            compute_store(out, (size_t)t0 * DMODEL, r, G, qA, kA, vA);
            break;
        }
    }
}

extern "C" void kernel_launch(void* const* d_in, const int* in_sizes, int n_in,
                              void* d_out, int out_size, void* d_ws, size_t ws_size,
                              hipStream_t stream) {
    const float* q = (const float*)d_in[0];
    const float* k = (const float*)d_in[1];
    const float* v = (const float*)d_in[2];
    float* o = (float*)d_out;
    const int ntok = in_sizes[0] / DMODEL;   // B*S = 32768
    temporal_attn_kernel<<<NBLK, 256, 0, stream>>>(q, k, v, o, ntok);
}